// Round 1
// baseline (1358.225 us; speedup 1.0000x reference)
//
#include <hip/hip_runtime.h>

#define BB 4
#define LL 4096
#define DD 512

constexpr float SCALE_INV = 0.0625f;  // 1/sqrt(HIDDEN_DIM=256)

// ---------------------------------------------------------------------------
// C[M,N] = A[M,512] @ W[N,512]^T  (both row-major, K-contiguous "NT" GEMM)
// 64x64 tile, 256 threads, 4x4 micro-tile, K staged in 16-wide LDS chunks
// stored transposed [16][68] so fragment reads are aligned float4 (b128).
// ---------------------------------------------------------------------------
__global__ __launch_bounds__(256) void gemm_nt(const float* __restrict__ A,
                                               const float* __restrict__ W,
                                               float* __restrict__ C, int N) {
    __shared__ float As[16][68];
    __shared__ float Ws[16][68];
    const int tid = threadIdx.x;
    const int tx = tid & 15, ty = tid >> 4;
    const int rowBase = blockIdx.x * 64;
    const int colBase = blockIdx.y * 64;
    const int lrow = tid >> 2;          // 0..63
    const int lc4 = (tid & 3) << 2;     // 0,4,8,12

    float acc[4][4] = {};
    const float* Aptr = A + (size_t)(rowBase + lrow) * DD + lc4;
    const float* Wptr = W + (size_t)(colBase + lrow) * DD + lc4;

    for (int dc = 0; dc < DD; dc += 16) {
        float4 a4 = *reinterpret_cast<const float4*>(Aptr + dc);
        float4 w4 = *reinterpret_cast<const float4*>(Wptr + dc);
        __syncthreads();  // previous iteration's reads must finish
        As[lc4 + 0][lrow] = a4.x; As[lc4 + 1][lrow] = a4.y;
        As[lc4 + 2][lrow] = a4.z; As[lc4 + 3][lrow] = a4.w;
        Ws[lc4 + 0][lrow] = w4.x; Ws[lc4 + 1][lrow] = w4.y;
        Ws[lc4 + 2][lrow] = w4.z; Ws[lc4 + 3][lrow] = w4.w;
        __syncthreads();
        #pragma unroll
        for (int t = 0; t < 16; ++t) {
            float4 q4 = *reinterpret_cast<const float4*>(&As[t][ty << 2]);
            float4 k4 = *reinterpret_cast<const float4*>(&Ws[t][tx << 2]);
            float q[4] = {q4.x, q4.y, q4.z, q4.w};
            float k[4] = {k4.x, k4.y, k4.z, k4.w};
            #pragma unroll
            for (int i = 0; i < 4; ++i)
                #pragma unroll
                for (int j = 0; j < 4; ++j)
                    acc[i][j] = fmaf(q[i], k[j], acc[i][j]);
        }
    }
    #pragma unroll
    for (int i = 0; i < 4; ++i)
        #pragma unroll
        for (int j = 0; j < 4; ++j)
            C[(size_t)(rowBase + (ty << 2) + i) * N + colBase + (tx << 2) + j] =
                acc[i][j];
}

// ---------------------------------------------------------------------------
// Fused: S[b,q,k] = Q[b,q]·K[b,k]/16 for all 4 batches of a 64x64 (q,k) tile,
// softmax across b per (q,k), mask over q rows, reduce over q into wsum[b,k].
// ---------------------------------------------------------------------------
__global__ __launch_bounds__(256) void scores_wsum(const float* __restrict__ Q,
                                                   const float* __restrict__ K,
                                                   const int* __restrict__ lens,
                                                   float* __restrict__ wsum) {
    __shared__ float Qs[16][68];
    __shared__ float Ks[16][68];
    __shared__ float red[4][4][4][16];  // [wave][b][j][tx]
    const int tid = threadIdx.x;
    const int tx = tid & 15, ty = tid >> 4;
    const int qBase = blockIdx.x * 64;
    const int kBase = blockIdx.y * 64;
    const int lrow = tid >> 2;
    const int lc4 = (tid & 3) << 2;

    float acc[4][4][4] = {};  // [b][i][j]

    #pragma unroll
    for (int b = 0; b < BB; ++b) {
        const float* Qp = Q + ((size_t)b * LL + qBase + lrow) * DD + lc4;
        const float* Kp = K + ((size_t)b * LL + kBase + lrow) * DD + lc4;
        for (int dc = 0; dc < DD; dc += 16) {
            float4 a4 = *reinterpret_cast<const float4*>(Qp + dc);
            float4 w4 = *reinterpret_cast<const float4*>(Kp + dc);
            __syncthreads();
            Qs[lc4 + 0][lrow] = a4.x; Qs[lc4 + 1][lrow] = a4.y;
            Qs[lc4 + 2][lrow] = a4.z; Qs[lc4 + 3][lrow] = a4.w;
            Ks[lc4 + 0][lrow] = w4.x; Ks[lc4 + 1][lrow] = w4.y;
            Ks[lc4 + 2][lrow] = w4.z; Ks[lc4 + 3][lrow] = w4.w;
            __syncthreads();
            #pragma unroll
            for (int t = 0; t < 16; ++t) {
                float4 q4 = *reinterpret_cast<const float4*>(&Qs[t][ty << 2]);
                float4 k4 = *reinterpret_cast<const float4*>(&Ks[t][tx << 2]);
                float q[4] = {q4.x, q4.y, q4.z, q4.w};
                float k[4] = {k4.x, k4.y, k4.z, k4.w};
                #pragma unroll
                for (int i = 0; i < 4; ++i)
                    #pragma unroll
                    for (int j = 0; j < 4; ++j)
                        acc[b][i][j] = fmaf(q[i], k[j], acc[b][i][j]);
            }
        }
    }

    int l0 = lens[0], l1 = lens[1], l2 = lens[2], l3 = lens[3];

    float psum[4][4] = {};  // [b][j] partial over this thread's 4 q rows
    #pragma unroll
    for (int i = 0; i < 4; ++i) {
        const int q = qBase + (ty << 2) + i;
        #pragma unroll
        for (int j = 0; j < 4; ++j) {
            float s0 = acc[0][i][j] * SCALE_INV;
            float s1 = acc[1][i][j] * SCALE_INV;
            float s2 = acc[2][i][j] * SCALE_INV;
            float s3 = acc[3][i][j] * SCALE_INV;
            float m = fmaxf(fmaxf(s0, s1), fmaxf(s2, s3));
            float e0 = __expf(s0 - m);
            float e1 = __expf(s1 - m);
            float e2 = __expf(s2 - m);
            float e3 = __expf(s3 - m);
            float inv = 1.0f / (e0 + e1 + e2 + e3);
            psum[0][j] += (q < l0) ? e0 * inv : 0.0f;
            psum[1][j] += (q < l1) ? e1 * inv : 0.0f;
            psum[2][j] += (q < l2) ? e2 * inv : 0.0f;
            psum[3][j] += (q < l3) ? e3 * inv : 0.0f;
        }
    }

    // Reduce over q rows: shuffle across the wave's 4 ty values, then LDS
    // across the 4 waves, then one global atomic per (b, k-in-tile).
    const int lane = tid & 63;
    const int wav = tid >> 6;
    #pragma unroll
    for (int b = 0; b < 4; ++b)
        #pragma unroll
        for (int j = 0; j < 4; ++j) {
            float v = psum[b][j];
            v += __shfl_xor(v, 16);
            v += __shfl_xor(v, 32);
            if (lane < 16) red[wav][b][j][lane] = v;
        }
    __syncthreads();
    {
        const int b = tid >> 6, j = (tid >> 4) & 3, txe = tid & 15;
        float v = red[0][b][j][txe] + red[1][b][j][txe] +
                  red[2][b][j][txe] + red[3][b][j][txe];
        atomicAdd(&wsum[b * LL + kBase + (txe << 2) + j], v);
    }
}

// y[b,e] = sum_k wsum[b,k] * X[b,k,e]   (k split across blocks, atomic acc)
__global__ __launch_bounds__(256) void wsum_x(const float* __restrict__ X,
                                              const float* __restrict__ wsum,
                                              float* __restrict__ y) {
    const int b = blockIdx.y;
    const int e = blockIdx.x * 256 + threadIdx.x;  // gridDim.x == 2
    const int kc = blockIdx.z * 64;                // gridDim.z == 64
    const float* Xp = X + ((size_t)b * LL + kc) * DD + e;
    const float* wp = wsum + b * LL + kc;
    float a = 0.0f;
    #pragma unroll 4
    for (int k = 0; k < 64; ++k) a = fmaf(wp[k], Xp[(size_t)k * DD], a);
    atomicAdd(&y[b * DD + e], a);
}

// out[b,d] = sum_e y[b,e] * Wv[d,e]
__global__ __launch_bounds__(256) void y_out(const float* __restrict__ Wv,
                                             const float* __restrict__ y,
                                             float* __restrict__ out) {
    const int b = blockIdx.y;
    const int d = blockIdx.x * 256 + threadIdx.x;  // gridDim.x == 2
    const float* wv = Wv + (size_t)d * DD;
    const float* yb = y + b * DD;
    float a = 0.0f;
    #pragma unroll 4
    for (int e = 0; e < DD; e += 4) {
        float4 w4 = *reinterpret_cast<const float4*>(wv + e);
        float4 y4 = *reinterpret_cast<const float4*>(yb + e);
        a += w4.x * y4.x + w4.y * y4.y + w4.z * y4.z + w4.w * y4.w;
    }
    out[b * DD + d] = a;
}

extern "C" void kernel_launch(void* const* d_in, const int* in_sizes, int n_in,
                              void* d_out, int out_size, void* d_ws, size_t ws_size,
                              hipStream_t stream) {
    const float* X  = (const float*)d_in[0];
    const float* Wq = (const float*)d_in[1];
    const float* Wk = (const float*)d_in[2];
    const float* Wv = (const float*)d_in[3];
    const int* lens = (const int*)d_in[4];
    float* out = (float*)d_out;

    char* ws = (char*)d_ws;
    float* Qb   = (float*)ws;                                  // 32 MB
    float* Kb   = (float*)(ws + ((size_t)32 << 20));           // 32 MB
    float* wsum = (float*)(ws + ((size_t)64 << 20));           // 64 KB
    float* y    = (float*)(ws + ((size_t)64 << 20) + 65536);   // 8 KB

    // zero wsum + y (contiguous); harness poisons ws with 0xAA each call
    hipMemsetAsync(wsum, 0,
                   (size_t)BB * LL * sizeof(float) + (size_t)BB * DD * sizeof(float),
                   stream);

    dim3 blk(256);
    gemm_nt<<<dim3(256, 8), blk, 0, stream>>>(X, Wq, Qb, DD);   // Q = X @ Wq^T
    gemm_nt<<<dim3(256, 8), blk, 0, stream>>>(X, Wk, Kb, DD);   // K = X @ Wk^T
    scores_wsum<<<dim3(64, 64), blk, 0, stream>>>(Qb, Kb, lens, wsum);
    wsum_x<<<dim3(2, 4, 64), blk, 0, stream>>>(X, wsum, y);
    y_out<<<dim3(2, 4), blk, 0, stream>>>(Wv, y, out);
}

// Round 2
// 563.133 us; speedup vs baseline: 2.4119x; 2.4119x over previous
//
#include <hip/hip_runtime.h>

#define BB 4
#define LL 4096
#define DD 512

typedef __attribute__((ext_vector_type(8))) short bf16x8;
typedef __attribute__((ext_vector_type(4))) float f32x4;
typedef __attribute__((ext_vector_type(4))) unsigned short ushort4v;

__device__ __forceinline__ unsigned short bf16_rne(float x) {
    unsigned u = __float_as_uint(x);
    unsigned r = (u + 0x7FFFu + ((u >> 16) & 1u)) >> 16;
    return (unsigned short)r;
}

// ---------------------------------------------------------------------------
// C[M,N] = scale * A[M,512] @ W[N,512]^T, written as bf16 hi/lo pair.
// fp32 FMA GEMM (64x64 tile, 256 threads, 4x4 micro-tile) — unchanged body,
// epilogue splits v = hi + lo into two bf16 arrays.
// ---------------------------------------------------------------------------
__global__ __launch_bounds__(256) void gemm_nt_split(
    const float* __restrict__ A, const float* __restrict__ W,
    unsigned short* __restrict__ Ch, unsigned short* __restrict__ Cl,
    float scale) {
    __shared__ float As[16][68];
    __shared__ float Ws[16][68];
    const int tid = threadIdx.x;
    const int tx = tid & 15, ty = tid >> 4;
    const int rowBase = blockIdx.x * 64;
    const int colBase = blockIdx.y * 64;
    const int lrow = tid >> 2;
    const int lc4 = (tid & 3) << 2;

    float acc[4][4] = {};
    const float* Aptr = A + (size_t)(rowBase + lrow) * DD + lc4;
    const float* Wptr = W + (size_t)(colBase + lrow) * DD + lc4;

    for (int dc = 0; dc < DD; dc += 16) {
        float4 a4 = *reinterpret_cast<const float4*>(Aptr + dc);
        float4 w4 = *reinterpret_cast<const float4*>(Wptr + dc);
        __syncthreads();
        As[lc4 + 0][lrow] = a4.x; As[lc4 + 1][lrow] = a4.y;
        As[lc4 + 2][lrow] = a4.z; As[lc4 + 3][lrow] = a4.w;
        Ws[lc4 + 0][lrow] = w4.x; Ws[lc4 + 1][lrow] = w4.y;
        Ws[lc4 + 2][lrow] = w4.z; Ws[lc4 + 3][lrow] = w4.w;
        __syncthreads();
        #pragma unroll
        for (int t = 0; t < 16; ++t) {
            float4 q4 = *reinterpret_cast<const float4*>(&As[t][ty << 2]);
            float4 k4 = *reinterpret_cast<const float4*>(&Ws[t][tx << 2]);
            float q[4] = {q4.x, q4.y, q4.z, q4.w};
            float k[4] = {k4.x, k4.y, k4.z, k4.w};
            #pragma unroll
            for (int i = 0; i < 4; ++i)
                #pragma unroll
                for (int j = 0; j < 4; ++j)
                    acc[i][j] = fmaf(q[i], k[j], acc[i][j]);
        }
    }
    #pragma unroll
    for (int i = 0; i < 4; ++i) {
        ushort4v h4, l4;
        #pragma unroll
        for (int j = 0; j < 4; ++j) {
            float v = acc[i][j] * scale;
            unsigned short h = bf16_rne(v);
            float lo = v - __uint_as_float((unsigned)h << 16);
            h4[j] = h;
            l4[j] = bf16_rne(lo);
        }
        size_t off = (size_t)(rowBase + (ty << 2) + i) * DD + colBase + (tx << 2);
        *reinterpret_cast<ushort4v*>(Ch + off) = h4;
        *reinterpret_cast<ushort4v*>(Cl + off) = l4;
    }
}

// ---------------------------------------------------------------------------
// Fused MFMA scores + batch-softmax + masked q-reduction into wsum[b,k].
// Tile: 128 q x 64 k, 4 waves (each 64q x 32k), BK=64 d-chunk.
// LDS: swizzled bf16 tiles staged via global_load_lds (linear dest,
// pre-swizzled source column; frag reads apply the same XOR).
// ---------------------------------------------------------------------------
#define GLOAD_LDS16(SRC, DST)                                                  \
    __builtin_amdgcn_global_load_lds(                                          \
        (const __attribute__((address_space(1))) void*)(SRC),                  \
        (__attribute__((address_space(3))) void*)(DST), 16, 0, 0)

// stage 8 rows x 64 bf16 cols (1 KB). lane ln: row r=ln>>3, 16B chunk c=ln&7.
// source column chunk = c ^ r (row0 must be a multiple of 8).
__device__ __forceinline__ void stage8(const unsigned short* __restrict__ g,
                                       unsigned short* l) {
    const int ln = threadIdx.x & 63;
    const int r = ln >> 3;
    const int c = ln & 7;
    const unsigned short* src = g + (size_t)r * DD + ((c ^ r) << 3);
    GLOAD_LDS16(src, l);
}

// read one 16x32 A/B fragment: lane holds row16+(lane&15), 8 bf16 at
// k = kk + (lane>>4)*8, with the read-side XOR swizzle.
__device__ __forceinline__ bf16x8 ldfrag(const unsigned short* base, int row16,
                                         int kk) {
    const int lane = threadIdx.x & 63;
    const int r = row16 + (lane & 15);
    const int boff = r * 128 + ((((kk + ((lane >> 4) << 3)) << 1)) ^ ((r & 7) << 4));
    return *reinterpret_cast<const bf16x8*>(
        reinterpret_cast<const char*>(base) + boff);
}

__global__ __launch_bounds__(256, 2) void scores_wsum(
    const unsigned short* __restrict__ Qh_g, const unsigned short* __restrict__ Ql_g,
    const unsigned short* __restrict__ Kh_g, const unsigned short* __restrict__ Kl_g,
    const int* __restrict__ lens, float* __restrict__ wsum) {
    __shared__ unsigned short Qh_s[128][64];
    __shared__ unsigned short Ql_s[128][64];
    __shared__ unsigned short Kh_s[64][64];
    __shared__ unsigned short Kl_s[64][64];

    const int qBase = blockIdx.x * 128;
    const int kBase = blockIdx.y * 64;
    const int w = threadIdx.x >> 6;
    const int lane = threadIdx.x & 63;
    const int wq = (w >> 1) * 64;   // 0 or 64
    const int wk = (w & 1) * 32;    // 0 or 32

    const int l0 = lens[0], l1 = lens[1], l2 = lens[2], l3 = lens[3];

    f32x4 acc[4][4][2] = {};  // [b][i(16q)][j(16k)]

    #pragma unroll
    for (int b = 0; b < BB; ++b) {
        const unsigned short* qh = Qh_g + (size_t)(b * LL + qBase) * DD;
        const unsigned short* ql = Ql_g + (size_t)(b * LL + qBase) * DD;
        const unsigned short* kh = Kh_g + (size_t)(b * LL + kBase) * DD;
        const unsigned short* kl = Kl_g + (size_t)(b * LL + kBase) * DD;
        for (int dcc = 0; dcc < 8; ++dcc) {
            const int dc = dcc << 6;
            __syncthreads();  // previous chunk's frag reads must finish
            // each wave stages: 32 Qh rows, 32 Ql rows, 16 Kh rows, 16 Kl rows
            #pragma unroll
            for (int s = 0; s < 4; ++s) {
                const int r0 = w * 32 + s * 8;
                stage8(qh + (size_t)r0 * DD + dc, &Qh_s[r0][0]);
                stage8(ql + (size_t)r0 * DD + dc, &Ql_s[r0][0]);
            }
            #pragma unroll
            for (int s = 0; s < 2; ++s) {
                const int r0 = w * 16 + s * 8;
                stage8(kh + (size_t)r0 * DD + dc, &Kh_s[r0][0]);
                stage8(kl + (size_t)r0 * DD + dc, &Kl_s[r0][0]);
            }
            __syncthreads();  // drains vmcnt (global_load_lds) before reads
            #pragma unroll
            for (int kk = 0; kk < 64; kk += 32) {
                bf16x8 bh0 = ldfrag(&Kh_s[0][0], wk + 0, kk);
                bf16x8 bh1 = ldfrag(&Kh_s[0][0], wk + 16, kk);
                bf16x8 bl0 = ldfrag(&Kl_s[0][0], wk + 0, kk);
                bf16x8 bl1 = ldfrag(&Kl_s[0][0], wk + 16, kk);
                #pragma unroll
                for (int i = 0; i < 4; ++i) {
                    bf16x8 ah = ldfrag(&Qh_s[0][0], wq + i * 16, kk);
                    bf16x8 al = ldfrag(&Ql_s[0][0], wq + i * 16, kk);
                    acc[b][i][0] = __builtin_amdgcn_mfma_f32_16x16x32_bf16(
                        ah, bh0, acc[b][i][0], 0, 0, 0);
                    acc[b][i][0] = __builtin_amdgcn_mfma_f32_16x16x32_bf16(
                        ah, bl0, acc[b][i][0], 0, 0, 0);
                    acc[b][i][0] = __builtin_amdgcn_mfma_f32_16x16x32_bf16(
                        al, bh0, acc[b][i][0], 0, 0, 0);
                    acc[b][i][1] = __builtin_amdgcn_mfma_f32_16x16x32_bf16(
                        ah, bh1, acc[b][i][1], 0, 0, 0);
                    acc[b][i][1] = __builtin_amdgcn_mfma_f32_16x16x32_bf16(
                        ah, bl1, acc[b][i][1], 0, 0, 0);
                    acc[b][i][1] = __builtin_amdgcn_mfma_f32_16x16x32_bf16(
                        al, bh1, acc[b][i][1], 0, 0, 0);
                }
            }
        }
    }

    // Epilogue: softmax across b per element (no max-subtract: |s| < ~12),
    // mask q rows, reduce over q, atomically add into wsum.
    float psum[4][2] = {};  // [b][j]
    #pragma unroll
    for (int i = 0; i < 4; ++i) {
        #pragma unroll
        for (int r = 0; r < 4; ++r) {
            const int q = qBase + wq + i * 16 + ((lane >> 4) << 2) + r;
            #pragma unroll
            for (int j = 0; j < 2; ++j) {
                float e0 = __expf(acc[0][i][j][r]);
                float e1 = __expf(acc[1][i][j][r]);
                float e2 = __expf(acc[2][i][j][r]);
                float e3 = __expf(acc[3][i][j][r]);
                float inv = 1.0f / (e0 + e1 + e2 + e3);
                psum[0][j] += (q < l0) ? e0 * inv : 0.0f;
                psum[1][j] += (q < l1) ? e1 * inv : 0.0f;
                psum[2][j] += (q < l2) ? e2 * inv : 0.0f;
                psum[3][j] += (q < l3) ? e3 * inv : 0.0f;
            }
        }
    }
    #pragma unroll
    for (int bb = 0; bb < 4; ++bb)
        #pragma unroll
        for (int j = 0; j < 2; ++j) {
            float v = psum[bb][j];
            v += __shfl_xor(v, 16);
            v += __shfl_xor(v, 32);
            if (lane < 16)
                atomicAdd(&wsum[bb * LL + kBase + wk + j * 16 + lane], v);
        }
}

// y[b,e] = sum_k wsum[b,k] * X[b,k,e]
__global__ __launch_bounds__(256) void wsum_x(const float* __restrict__ X,
                                              const float* __restrict__ wsum,
                                              float* __restrict__ y) {
    const int b = blockIdx.y;
    const int e = blockIdx.x * 256 + threadIdx.x;
    const int kc = blockIdx.z * 64;
    const float* Xp = X + ((size_t)b * LL + kc) * DD + e;
    const float* wp = wsum + b * LL + kc;
    float a = 0.0f;
    #pragma unroll 4
    for (int k = 0; k < 64; ++k) a = fmaf(wp[k], Xp[(size_t)k * DD], a);
    atomicAdd(&y[b * DD + e], a);
}

// out[b,d] = sum_e y[b,e] * Wv[d,e]
__global__ __launch_bounds__(256) void y_out(const float* __restrict__ Wv,
                                             const float* __restrict__ y,
                                             float* __restrict__ out) {
    const int b = blockIdx.y;
    const int d = blockIdx.x * 256 + threadIdx.x;
    const float* wv = Wv + (size_t)d * DD;
    const float* yb = y + b * DD;
    float a = 0.0f;
    #pragma unroll 4
    for (int e = 0; e < DD; e += 4) {
        float4 w4 = *reinterpret_cast<const float4*>(wv + e);
        float4 y4 = *reinterpret_cast<const float4*>(yb + e);
        a += w4.x * y4.x + w4.y * y4.y + w4.z * y4.z + w4.w * y4.w;
    }
    out[b * DD + d] = a;
}

extern "C" void kernel_launch(void* const* d_in, const int* in_sizes, int n_in,
                              void* d_out, int out_size, void* d_ws, size_t ws_size,
                              hipStream_t stream) {
    const float* X  = (const float*)d_in[0];
    const float* Wq = (const float*)d_in[1];
    const float* Wk = (const float*)d_in[2];
    const float* Wv = (const float*)d_in[3];
    const int* lens = (const int*)d_in[4];
    float* out = (float*)d_out;

    char* ws = (char*)d_ws;
    unsigned short* Qh = (unsigned short*)ws;                          // 16 MB
    unsigned short* Ql = (unsigned short*)(ws + ((size_t)16 << 20));   // 16 MB
    unsigned short* Kh = (unsigned short*)(ws + ((size_t)32 << 20));   // 16 MB
    unsigned short* Kl = (unsigned short*)(ws + ((size_t)48 << 20));   // 16 MB
    float* wsum = (float*)(ws + ((size_t)64 << 20));                   // 64 KB
    float* y    = (float*)(ws + ((size_t)64 << 20) + 65536);           // 8 KB

    hipMemsetAsync(wsum, 0,
                   (size_t)BB * LL * sizeof(float) + (size_t)BB * DD * sizeof(float),
                   stream);

    dim3 blk(256);
    // scale 1/16 folded into Q's hi/lo split
    gemm_nt_split<<<dim3(256, 8), blk, 0, stream>>>(X, Wq, Qh, Ql, 0.0625f);
    gemm_nt_split<<<dim3(256, 8), blk, 0, stream>>>(X, Wk, Kh, Kl, 1.0f);
    scores_wsum<<<dim3(32, 64), blk, 0, stream>>>(Qh, Ql, Kh, Kl, lens, wsum);
    wsum_x<<<dim3(2, 4, 64), blk, 0, stream>>>(X, wsum, y);
    y_out<<<dim3(2, 4), blk, 0, stream>>>(Wv, y, out);
}

// Round 3
// 374.893 us; speedup vs baseline: 3.6230x; 1.5021x over previous
//
#include <hip/hip_runtime.h>

#define BB 4
#define LL 4096
#define DD 512

typedef __attribute__((ext_vector_type(8))) short bf16x8;
typedef __attribute__((ext_vector_type(4))) float f32x4;
typedef __attribute__((ext_vector_type(4))) unsigned short ushort4v;

__device__ __forceinline__ unsigned short bf16_rne(float x) {
    unsigned u = __float_as_uint(x);
    unsigned r = (u + 0x7FFFu + ((u >> 16) & 1u)) >> 16;
    return (unsigned short)r;
}

// ---------------------------------------------------------------------------
// split_x: X fp32 -> (Xh, Xl) bf16 hi/lo pair. 4 elems/thread.
// ---------------------------------------------------------------------------
__global__ __launch_bounds__(256) void split_x(const float* __restrict__ X,
                                               unsigned short* __restrict__ Xh,
                                               unsigned short* __restrict__ Xl) {
    const size_t i = ((size_t)blockIdx.x * 256 + threadIdx.x) * 4;
    float4 x4 = *reinterpret_cast<const float4*>(X + i);
    float v[4] = {x4.x, x4.y, x4.z, x4.w};
    ushort4v h4, l4;
    #pragma unroll
    for (int j = 0; j < 4; ++j) {
        unsigned short h = bf16_rne(v[j]);
        float lo = v[j] - __uint_as_float((unsigned)h << 16);
        h4[j] = h;
        l4[j] = bf16_rne(lo);
    }
    *reinterpret_cast<ushort4v*>(Xh + i) = h4;
    *reinterpret_cast<ushort4v*>(Xl + i) = l4;
}

// ---------------------------------------------------------------------------
// Mt[i,j] = scale * sum_d A[d,i] * B[d,j]   (A=Wk, B=Wq gives Mt = (Wq^T Wk)^T)
// fp32 64x64 tile, hi/lo bf16 epilogue. 0.27 GFLOP — latency-trivial.
// ---------------------------------------------------------------------------
__global__ __launch_bounds__(256) void gemm_tn_M(const float* __restrict__ A,
                                                 const float* __restrict__ B,
                                                 unsigned short* __restrict__ Mh,
                                                 unsigned short* __restrict__ Ml,
                                                 float scale) {
    __shared__ float As[16][68];
    __shared__ float Bs[16][68];
    const int tid = threadIdx.x;
    const int tx = tid & 15, ty = tid >> 4;
    const int iBase = blockIdx.x * 64;
    const int jBase = blockIdx.y * 64;
    const int dr = tid >> 4;            // 0..15
    const int c4 = (tid & 15) << 2;     // 0..60

    float acc[4][4] = {};
    for (int d0 = 0; d0 < DD; d0 += 16) {
        float4 a4 = *reinterpret_cast<const float4*>(A + (size_t)(d0 + dr) * DD + iBase + c4);
        float4 b4 = *reinterpret_cast<const float4*>(B + (size_t)(d0 + dr) * DD + jBase + c4);
        __syncthreads();
        *reinterpret_cast<float4*>(&As[dr][c4]) = a4;
        *reinterpret_cast<float4*>(&Bs[dr][c4]) = b4;
        __syncthreads();
        #pragma unroll
        for (int t = 0; t < 16; ++t) {
            float4 q4 = *reinterpret_cast<const float4*>(&As[t][ty << 2]);
            float4 k4 = *reinterpret_cast<const float4*>(&Bs[t][tx << 2]);
            float q[4] = {q4.x, q4.y, q4.z, q4.w};
            float k[4] = {k4.x, k4.y, k4.z, k4.w};
            #pragma unroll
            for (int i = 0; i < 4; ++i)
                #pragma unroll
                for (int j = 0; j < 4; ++j)
                    acc[i][j] = fmaf(q[i], k[j], acc[i][j]);
        }
    }
    #pragma unroll
    for (int i = 0; i < 4; ++i)
        #pragma unroll
        for (int j = 0; j < 4; ++j) {
            float v = acc[i][j] * scale;
            unsigned short h = bf16_rne(v);
            float lo = v - __uint_as_float((unsigned)h << 16);
            size_t off = (size_t)(iBase + (ty << 2) + i) * DD + jBase + (tx << 2) + j;
            Mh[off] = h;
            Ml[off] = bf16_rne(lo);
        }
}

// ---------------------------------------------------------------------------
// Shared MFMA staging helpers (validated in round 2).
// ---------------------------------------------------------------------------
#define GLOAD_LDS16(SRC, DST)                                                  \
    __builtin_amdgcn_global_load_lds(                                          \
        (const __attribute__((address_space(1))) void*)(SRC),                  \
        (__attribute__((address_space(3))) void*)(DST), 16, 0, 0)

// stage 8 rows x 64 bf16 cols (1 KB), linear LDS dest, source column chunk
// pre-swizzled c^r (row0 must be a multiple of 8).
__device__ __forceinline__ void stage8(const unsigned short* __restrict__ g,
                                       unsigned short* l) {
    const int ln = threadIdx.x & 63;
    const int r = ln >> 3;
    const int c = ln & 7;
    const unsigned short* src = g + (size_t)r * DD + ((c ^ r) << 3);
    GLOAD_LDS16(src, l);
}

// read one 16x32 fragment with the read-side XOR swizzle.
__device__ __forceinline__ bf16x8 ldfrag(const unsigned short* base, int row16,
                                         int kk) {
    const int lane = threadIdx.x & 63;
    const int r = row16 + (lane & 15);
    const int boff = r * 128 + ((((kk + ((lane >> 4) << 3)) << 1)) ^ ((r & 7) << 4));
    return *reinterpret_cast<const bf16x8*>(
        reinterpret_cast<const char*>(base) + boff);
}

// ---------------------------------------------------------------------------
// T = Xsplit @ Mtsplit^T ("NT"): T[i,f] = sum_e X[i,e] Mt[f,e].
// Tile 128 x 64, 4 waves, 3-product bf16 split, hi/lo epilogue.
// ---------------------------------------------------------------------------
__global__ __launch_bounds__(256, 3) void gemm_nt_T(
    const unsigned short* __restrict__ Xh_g, const unsigned short* __restrict__ Xl_g,
    const unsigned short* __restrict__ Mh_g, const unsigned short* __restrict__ Ml_g,
    unsigned short* __restrict__ Th_g, unsigned short* __restrict__ Tl_g) {
    __shared__ unsigned short Ah_s[128][64];
    __shared__ unsigned short Al_s[128][64];
    __shared__ unsigned short Bh_s[64][64];
    __shared__ unsigned short Bl_s[64][64];

    const int rBase = blockIdx.x * 128;
    const int cBase = blockIdx.y * 64;
    const int w = threadIdx.x >> 6;
    const int lane = threadIdx.x & 63;
    const int wq = (w >> 1) * 64;
    const int wk = (w & 1) * 32;

    f32x4 acc[4][2] = {};

    for (int dcc = 0; dcc < 8; ++dcc) {
        const int dc = dcc << 6;
        __syncthreads();
        #pragma unroll
        for (int s = 0; s < 4; ++s) {
            const int r0 = w * 32 + s * 8;
            stage8(Xh_g + (size_t)(rBase + r0) * DD + dc, &Ah_s[r0][0]);
            stage8(Xl_g + (size_t)(rBase + r0) * DD + dc, &Al_s[r0][0]);
        }
        #pragma unroll
        for (int s = 0; s < 2; ++s) {
            const int r0 = w * 16 + s * 8;
            stage8(Mh_g + (size_t)(cBase + r0) * DD + dc, &Bh_s[r0][0]);
            stage8(Ml_g + (size_t)(cBase + r0) * DD + dc, &Bl_s[r0][0]);
        }
        __syncthreads();
        #pragma unroll
        for (int kk = 0; kk < 64; kk += 32) {
            bf16x8 bh0 = ldfrag(&Bh_s[0][0], wk + 0, kk);
            bf16x8 bh1 = ldfrag(&Bh_s[0][0], wk + 16, kk);
            bf16x8 bl0 = ldfrag(&Bl_s[0][0], wk + 0, kk);
            bf16x8 bl1 = ldfrag(&Bl_s[0][0], wk + 16, kk);
            #pragma unroll
            for (int i = 0; i < 4; ++i) {
                bf16x8 ah = ldfrag(&Ah_s[0][0], wq + i * 16, kk);
                bf16x8 al = ldfrag(&Al_s[0][0], wq + i * 16, kk);
                acc[i][0] = __builtin_amdgcn_mfma_f32_16x16x32_bf16(ah, bh0, acc[i][0], 0, 0, 0);
                acc[i][0] = __builtin_amdgcn_mfma_f32_16x16x32_bf16(ah, bl0, acc[i][0], 0, 0, 0);
                acc[i][0] = __builtin_amdgcn_mfma_f32_16x16x32_bf16(al, bh0, acc[i][0], 0, 0, 0);
                acc[i][1] = __builtin_amdgcn_mfma_f32_16x16x32_bf16(ah, bh1, acc[i][1], 0, 0, 0);
                acc[i][1] = __builtin_amdgcn_mfma_f32_16x16x32_bf16(ah, bl1, acc[i][1], 0, 0, 0);
                acc[i][1] = __builtin_amdgcn_mfma_f32_16x16x32_bf16(al, bh1, acc[i][1], 0, 0, 0);
            }
        }
    }

    #pragma unroll
    for (int i = 0; i < 4; ++i)
        #pragma unroll
        for (int r = 0; r < 4; ++r) {
            const int row = rBase + wq + i * 16 + ((lane >> 4) << 2) + r;
            #pragma unroll
            for (int j = 0; j < 2; ++j) {
                const int col = cBase + wk + j * 16 + (lane & 15);
                float v = acc[i][j][r];
                unsigned short h = bf16_rne(v);
                float lo = v - __uint_as_float((unsigned)h << 16);
                Th_g[(size_t)row * DD + col] = h;
                Tl_g[(size_t)row * DD + col] = bf16_rne(lo);
            }
        }
}

// ---------------------------------------------------------------------------
// Fused MFMA scores + batch-softmax + masked q-reduction (unchanged, r2-valid).
// S = T @ X^T per batch. Q-side = T, K-side = X.
// ---------------------------------------------------------------------------
__global__ __launch_bounds__(256, 3) void scores_wsum(
    const unsigned short* __restrict__ Qh_g, const unsigned short* __restrict__ Ql_g,
    const unsigned short* __restrict__ Kh_g, const unsigned short* __restrict__ Kl_g,
    const int* __restrict__ lens, float* __restrict__ wsum) {
    __shared__ unsigned short Qh_s[128][64];
    __shared__ unsigned short Ql_s[128][64];
    __shared__ unsigned short Kh_s[64][64];
    __shared__ unsigned short Kl_s[64][64];

    const int qBase = blockIdx.x * 128;
    const int kBase = blockIdx.y * 64;
    const int w = threadIdx.x >> 6;
    const int lane = threadIdx.x & 63;
    const int wq = (w >> 1) * 64;
    const int wk = (w & 1) * 32;

    const int l0 = lens[0], l1 = lens[1], l2 = lens[2], l3 = lens[3];

    f32x4 acc[4][4][2] = {};  // [b][i][j]

    #pragma unroll
    for (int b = 0; b < BB; ++b) {
        const unsigned short* qh = Qh_g + (size_t)(b * LL + qBase) * DD;
        const unsigned short* ql = Ql_g + (size_t)(b * LL + qBase) * DD;
        const unsigned short* kh = Kh_g + (size_t)(b * LL + kBase) * DD;
        const unsigned short* kl = Kl_g + (size_t)(b * LL + kBase) * DD;
        for (int dcc = 0; dcc < 8; ++dcc) {
            const int dc = dcc << 6;
            __syncthreads();
            #pragma unroll
            for (int s = 0; s < 4; ++s) {
                const int r0 = w * 32 + s * 8;
                stage8(qh + (size_t)r0 * DD + dc, &Qh_s[r0][0]);
                stage8(ql + (size_t)r0 * DD + dc, &Ql_s[r0][0]);
            }
            #pragma unroll
            for (int s = 0; s < 2; ++s) {
                const int r0 = w * 16 + s * 8;
                stage8(kh + (size_t)r0 * DD + dc, &Kh_s[r0][0]);
                stage8(kl + (size_t)r0 * DD + dc, &Kl_s[r0][0]);
            }
            __syncthreads();
            #pragma unroll
            for (int kk = 0; kk < 64; kk += 32) {
                bf16x8 bh0 = ldfrag(&Kh_s[0][0], wk + 0, kk);
                bf16x8 bh1 = ldfrag(&Kh_s[0][0], wk + 16, kk);
                bf16x8 bl0 = ldfrag(&Kl_s[0][0], wk + 0, kk);
                bf16x8 bl1 = ldfrag(&Kl_s[0][0], wk + 16, kk);
                #pragma unroll
                for (int i = 0; i < 4; ++i) {
                    bf16x8 ah = ldfrag(&Qh_s[0][0], wq + i * 16, kk);
                    bf16x8 al = ldfrag(&Ql_s[0][0], wq + i * 16, kk);
                    acc[b][i][0] = __builtin_amdgcn_mfma_f32_16x16x32_bf16(ah, bh0, acc[b][i][0], 0, 0, 0);
                    acc[b][i][0] = __builtin_amdgcn_mfma_f32_16x16x32_bf16(ah, bl0, acc[b][i][0], 0, 0, 0);
                    acc[b][i][0] = __builtin_amdgcn_mfma_f32_16x16x32_bf16(al, bh0, acc[b][i][0], 0, 0, 0);
                    acc[b][i][1] = __builtin_amdgcn_mfma_f32_16x16x32_bf16(ah, bh1, acc[b][i][1], 0, 0, 0);
                    acc[b][i][1] = __builtin_amdgcn_mfma_f32_16x16x32_bf16(ah, bl1, acc[b][i][1], 0, 0, 0);
                    acc[b][i][1] = __builtin_amdgcn_mfma_f32_16x16x32_bf16(al, bh1, acc[b][i][1], 0, 0, 0);
                }
            }
        }
    }

    float psum[4][2] = {};
    #pragma unroll
    for (int i = 0; i < 4; ++i) {
        #pragma unroll
        for (int r = 0; r < 4; ++r) {
            const int q = qBase + wq + i * 16 + ((lane >> 4) << 2) + r;
            #pragma unroll
            for (int j = 0; j < 2; ++j) {
                float e0 = __expf(acc[0][i][j][r]);
                float e1 = __expf(acc[1][i][j][r]);
                float e2 = __expf(acc[2][i][j][r]);
                float e3 = __expf(acc[3][i][j][r]);
                float inv = 1.0f / (e0 + e1 + e2 + e3);
                psum[0][j] += (q < l0) ? e0 * inv : 0.0f;
                psum[1][j] += (q < l1) ? e1 * inv : 0.0f;
                psum[2][j] += (q < l2) ? e2 * inv : 0.0f;
                psum[3][j] += (q < l3) ? e3 * inv : 0.0f;
            }
        }
    }
    #pragma unroll
    for (int bb = 0; bb < 4; ++bb)
        #pragma unroll
        for (int j = 0; j < 2; ++j) {
            float v = psum[bb][j];
            v += __shfl_xor(v, 16);
            v += __shfl_xor(v, 32);
            if (lane < 16)
                atomicAdd(&wsum[bb * LL + kBase + wk + j * 16 + lane], v);
        }
}

// y[b,e] = sum_k wsum[b,k] * X[b,k,e]
__global__ __launch_bounds__(256) void wsum_x(const float* __restrict__ X,
                                              const float* __restrict__ wsum,
                                              float* __restrict__ y) {
    const int b = blockIdx.y;
    const int e = blockIdx.x * 256 + threadIdx.x;
    const int kc = blockIdx.z * 64;
    const float* Xp = X + ((size_t)b * LL + kc) * DD + e;
    const float* wp = wsum + b * LL + kc;
    float a = 0.0f;
    #pragma unroll 4
    for (int k = 0; k < 64; ++k) a = fmaf(wp[k], Xp[(size_t)k * DD], a);
    atomicAdd(&y[b * DD + e], a);
}

// out[b,d] = sum_e y[b,e] * Wv[d,e]
__global__ __launch_bounds__(256) void y_out(const float* __restrict__ Wv,
                                             const float* __restrict__ y,
                                             float* __restrict__ out) {
    const int b = blockIdx.y;
    const int d = blockIdx.x * 256 + threadIdx.x;
    const float* wv = Wv + (size_t)d * DD;
    const float* yb = y + b * DD;
    float a = 0.0f;
    #pragma unroll 4
    for (int e = 0; e < DD; e += 4) {
        float4 w4 = *reinterpret_cast<const float4*>(wv + e);
        float4 y4 = *reinterpret_cast<const float4*>(yb + e);
        a += w4.x * y4.x + w4.y * y4.y + w4.z * y4.z + w4.w * y4.w;
    }
    out[b * DD + d] = a;
}

extern "C" void kernel_launch(void* const* d_in, const int* in_sizes, int n_in,
                              void* d_out, int out_size, void* d_ws, size_t ws_size,
                              hipStream_t stream) {
    const float* X  = (const float*)d_in[0];
    const float* Wq = (const float*)d_in[1];
    const float* Wk = (const float*)d_in[2];
    const float* Wv = (const float*)d_in[3];
    const int* lens = (const int*)d_in[4];
    float* out = (float*)d_out;

    char* ws = (char*)d_ws;
    unsigned short* Xh  = (unsigned short*)ws;                              // 16 MB
    unsigned short* Xl  = (unsigned short*)(ws + ((size_t)16 << 20));       // 16 MB
    unsigned short* Th  = (unsigned short*)(ws + ((size_t)32 << 20));       // 16 MB
    unsigned short* Tl  = (unsigned short*)(ws + ((size_t)48 << 20));       // 16 MB
    unsigned short* Mth = (unsigned short*)(ws + ((size_t)64 << 20));       // 512 KB
    unsigned short* Mtl = (unsigned short*)(ws + ((size_t)64 << 20) + (512u << 10));
    float* wsum = (float*)(ws + ((size_t)65 << 20));                        // 64 KB
    float* y    = (float*)(ws + ((size_t)65 << 20) + 65536);                // 8 KB

    hipMemsetAsync(wsum, 0,
                   (size_t)BB * LL * sizeof(float) + (size_t)BB * DD * sizeof(float),
                   stream);

    dim3 blk(256);
    split_x<<<dim3(8192), blk, 0, stream>>>(X, Xh, Xl);
    // Mt[f,e] = sum_d Wk[d,f] Wq[d,e] = (Wq^T Wk)^T, scale 1/16 folded in
    gemm_tn_M<<<dim3(8, 8), blk, 0, stream>>>(Wk, Wq, Mth, Mtl, 0.0625f);
    // T[i,f] = sum_e X[i,e] Mt[f,e]
    gemm_nt_T<<<dim3(128, 8), blk, 0, stream>>>(Xh, Xl, Mth, Mtl, Th, Tl);
    // S = T X^T, softmax over b, masked q-reduce
    scores_wsum<<<dim3(32, 64), blk, 0, stream>>>(Th, Tl, Xh, Xl, lens, wsum);
    wsum_x<<<dim3(2, 4, 64), blk, 0, stream>>>(X, wsum, y);
    y_out<<<dim3(2, 4), blk, 0, stream>>>(Wv, y, out);
}